// Round 2
// baseline (1140.588 us; speedup 1.0000x reference)
//
#include <hip/hip_runtime.h>
#include <cstdint>
#include <cstddef>

#define T_STEPS 50
#define B_SZ    1024
#define N_INP   784
#define H_SZ    256
#define L_SZ    10
#define T_CHUNK 10              // 5 chunks of 10 steps
#define M_CHUNK (T_CHUNK * B_SZ)  // 10240 rows per chunk

// ---------------------------------------------------------------------------
// Phase 0: transpose Wr[h][k] (256x256, fp32) -> WrT[k][h]. fp32->fp64 convert
// at use is exact, so WrT stays fp32 (half the gather bytes).
// ---------------------------------------------------------------------------
__global__ __launch_bounds__(256) void transpose_wr(const float* __restrict__ Wr,
                                                    float* __restrict__ WrT) {
    __shared__ float tile[32][33];
    int bx = blockIdx.x * 32, by = blockIdx.y * 32;
    int tx = threadIdx.x % 32, ty = threadIdx.x / 32;   // 32 x 8
    #pragma unroll
    for (int j = 0; j < 32; j += 8)
        tile[ty + j][tx] = Wr[(size_t)(by + ty + j) * H_SZ + bx + tx];
    __syncthreads();
    #pragma unroll
    for (int j = 0; j < 32; j += 8)
        WrT[(size_t)(bx + ty + j) * H_SZ + by + tx] = tile[tx][ty + j];
}

// ---------------------------------------------------------------------------
// Phase 1 (per chunk): cur[m][h] = sum_k X[m][k] * Wi[h][k], fp64 accumulate.
//   X chunk: [10240][784] fp32 (binary),  Wi: [256][784] fp32
// BM=64 BN=64 BK=16, 256 threads, 4x4 doubles per thread. LDS tiles kept in
// fp32 (exact convert at use). Accumulation order: sequential over k within
// each output -> deterministic, ~1ulp of exact.
// ---------------------------------------------------------------------------
#define GBM 64
#define GBN 64
#define GBK 16

__global__ __launch_bounds__(256) void gemm_xwi_f64(const float* __restrict__ X,
                                                    const float* __restrict__ Wi,
                                                    double* __restrict__ cur) {
    __shared__ float As[GBK][GBM + 4];
    __shared__ float Bs[GBK][GBN + 4];

    const int bm = blockIdx.x * GBM;    // 160 m-tiles
    const int bn = blockIdx.y * GBN;    // 4 n-tiles
    const int tid = threadIdx.x;
    const int tx = tid % 16;            // n: 16*4 = 64
    const int ty = tid / 16;            // m: 16*4 = 64

    double acc[4][4] = {};

    const float* Arow = X  + (size_t)bm * N_INP;
    const float* Brow = Wi + (size_t)bn * N_INP;

    for (int k0 = 0; k0 < N_INP; k0 += GBK) {
        // stage A: 64 rows x 16 k = 256 float4, one per thread
        {
            int r = tid >> 2, kc = (tid & 3) * 4;
            float4 va = *(const float4*)(Arow + (size_t)r * N_INP + k0 + kc);
            As[kc + 0][r] = va.x; As[kc + 1][r] = va.y;
            As[kc + 2][r] = va.z; As[kc + 3][r] = va.w;
            float4 vb = *(const float4*)(Brow + (size_t)r * N_INP + k0 + kc);
            Bs[kc + 0][r] = vb.x; Bs[kc + 1][r] = vb.y;
            Bs[kc + 2][r] = vb.z; Bs[kc + 3][r] = vb.w;
        }
        __syncthreads();

        #pragma unroll
        for (int kk = 0; kk < GBK; ++kk) {
            double a[4], b[4];
            #pragma unroll
            for (int im = 0; im < 4; ++im) a[im] = (double)As[kk][ty * 4 + im];
            #pragma unroll
            for (int in = 0; in < 4; ++in) b[in] = (double)Bs[kk][tx * 4 + in];
            #pragma unroll
            for (int im = 0; im < 4; ++im)
                #pragma unroll
                for (int in = 0; in < 4; ++in)
                    acc[im][in] = fma(a[im], b[in], acc[im][in]);
        }
        __syncthreads();
    }

    #pragma unroll
    for (int im = 0; im < 4; ++im) {
        int m = bm + ty * 4 + im;
        double* dst = cur + (size_t)m * H_SZ + bn + tx * 4;
        dst[0] = acc[im][0]; dst[1] = acc[im][1];
        dst[2] = acc[im][2]; dst[3] = acc[im][3];
    }
}

// ---------------------------------------------------------------------------
// Phase 2 (per chunk): 10 LIF steps in fp64. One block per batch, thread h
// owns neuron h. State (v, syn, spike-count, spike mask) persists in ws
// across chunk launches. Constants are the exact doubles numpy produces:
//   DT*TAU_MEM_INV = 0.001*50.0  -> double(0.05)
//   1.0-DT*TAU_SYN_INV = 1.0-0.1 -> double(0.9)
// ---------------------------------------------------------------------------
__global__ __launch_bounds__(256) void snn_steps(const double* __restrict__ cur,
                                                 const float* __restrict__ WrT,
                                                 const float* __restrict__ Wout,
                                                 const float* __restrict__ bout,
                                                 float* __restrict__ out,
                                                 double* __restrict__ v_st,
                                                 double* __restrict__ syn_st,
                                                 int* __restrict__ cnt_st,
                                                 unsigned long long* __restrict__ zmask_st,
                                                 int init, int fin) {
    const int b = blockIdx.x;
    const int h = threadIdx.x;

    __shared__ unsigned long long zmaskS[4];
    __shared__ int cntS[H_SZ];

    double v, syn;
    int cnt;
    if (init) {
        if (h < 4) zmaskS[h] = 0ull;
        v = 0.0; syn = 0.0; cnt = 0;
    } else {
        if (h < 4) zmaskS[h] = zmask_st[(size_t)b * 4 + h];
        v   = v_st[(size_t)b * H_SZ + h];
        syn = syn_st[(size_t)b * H_SZ + h];
        cnt = cnt_st[(size_t)b * H_SZ + h];
    }
    __syncthreads();

    const double* curb = cur + (size_t)b * H_SZ + h;

    for (int t = 0; t < T_CHUNK; ++t) {
        // LIF dynamics, reference op order, fp64
        double v_dec = v + 0.05 * ((0.0 - v) + syn);  // v + dt*tau_mem_inv*((v_leak-v)+i)
        double i_dec = 0.9 * syn;                     // i * (1 - dt*tau_syn_inv)
        bool   z_new = (v_dec - 0.5) > 0.0;           // superspike fwd
        v = z_new ? 0.0 : v_dec;                      // reset
        cnt += z_new ? 1 : 0;

        // recurrent drive from z_prev (mask in LDS), fp64 accumulate
        double rec = 0.0;
        #pragma unroll
        for (int w = 0; w < 4; ++w) {
            unsigned long long m = zmaskS[w];
            while (m) {
                int k = (w << 6) + __ffsll(m) - 1;
                m &= m - 1;
                rec += (double)WrT[(size_t)k * H_SZ + h];   // coalesced, exact cvt
            }
        }

        double inp = curb[(size_t)t * B_SZ * H_SZ];

        __syncthreads();                                    // reads of z_prev done
        unsigned long long bal = __ballot((int)z_new);
        if ((h & 63) == 0) zmaskS[h >> 6] = bal;
        __syncthreads();                                    // z_new visible

        syn = (i_dec + inp) + rec;                          // (i_dec + x@WiT) + z@WrT
    }

    // persist state
    v_st[(size_t)b * H_SZ + h]   = v;
    syn_st[(size_t)b * H_SZ + h] = syn;
    cnt_st[(size_t)b * H_SZ + h] = cnt;
    if (h < 4) zmask_st[(size_t)b * 4 + h] = zmaskS[h];

    if (fin) {
        cntS[h] = cnt;
        __syncthreads();
        if (h < L_SZ) {
            double s = 0.0;
            for (int k = 0; k < H_SZ; ++k)
                s += (double)cntS[k] * (double)Wout[(size_t)h * H_SZ + k];
            s += (double)T_STEPS * (double)bout[h];
            out[(size_t)b * L_SZ + h] = (float)(s / (double)T_STEPS);
        }
    }
}

// ---------------------------------------------------------------------------
extern "C" void kernel_launch(void* const* d_in, const int* in_sizes, int n_in,
                              void* d_out, int out_size, void* d_ws, size_t ws_size,
                              hipStream_t stream) {
    const float* x    = (const float*)d_in[0];   // [50,1024,784]
    const float* Wi   = (const float*)d_in[1];   // [256,784]
    const float* Wr   = (const float*)d_in[2];   // [256,256]
    const float* Wout = (const float*)d_in[3];   // [10,256]
    const float* bout = (const float*)d_in[4];   // [10]
    float* out = (float*)d_out;                  // [1024,10]

    // ws layout (26.5 MB total; <= ~53 MB proven safe in round 0/1)
    char* ws = (char*)d_ws;
    double*             cur_c    = (double*)(ws);                         // 20,971,520 B
    double*             v_st     = (double*)(ws + 20971520);              //  2,097,152 B
    double*             syn_st   = (double*)(ws + 23068672);              //  2,097,152 B
    int*                cnt_st   = (int*)   (ws + 25165824);              //  1,048,576 B
    unsigned long long* zmask_st = (unsigned long long*)(ws + 26214400);  //     32,768 B
    float*              WrT      = (float*) (ws + 26247168);              //    262,144 B

    hipLaunchKernelGGL(transpose_wr, dim3(8, 8), dim3(256), 0, stream, Wr, WrT);

    for (int c = 0; c < 5; ++c) {
        const float* xc = x + (size_t)c * M_CHUNK * N_INP;
        hipLaunchKernelGGL(gemm_xwi_f64, dim3(M_CHUNK / GBM, H_SZ / GBN), dim3(256),
                           0, stream, xc, Wi, cur_c);
        hipLaunchKernelGGL(snn_steps, dim3(B_SZ), dim3(256), 0, stream,
                           cur_c, WrT, Wout, bout, out,
                           v_st, syn_st, cnt_st, zmask_st,
                           (c == 0) ? 1 : 0, (c == 4) ? 1 : 0);
    }
}

// Round 3
// 1087.689 us; speedup vs baseline: 1.0486x; 1.0486x over previous
//
#include <hip/hip_runtime.h>
#include <cstdint>
#include <cstddef>

#define T_STEPS 50
#define B_SZ    1024
#define N_INP   784
#define H_SZ    256
#define L_SZ    10
#define T_CHUNK 10                 // 5 chunks of 10 steps
#define M_CHUNK (T_CHUNK * B_SZ)   // 10240 rows per chunk

// ---------------------------------------------------------------------------
// Phase 0: transpose Wr[h][k] (256x256, fp32) -> WrT[k][h].
// ---------------------------------------------------------------------------
__global__ __launch_bounds__(256) void transpose_wr(const float* __restrict__ Wr,
                                                    float* __restrict__ WrT) {
    __shared__ float tile[32][33];
    int bx = blockIdx.x * 32, by = blockIdx.y * 32;
    int tx = threadIdx.x % 32, ty = threadIdx.x / 32;   // 32 x 8
    #pragma unroll
    for (int j = 0; j < 32; j += 8)
        tile[ty + j][tx] = Wr[(size_t)(by + ty + j) * H_SZ + bx + tx];
    __syncthreads();
    #pragma unroll
    for (int j = 0; j < 32; j += 8)
        WrT[(size_t)(bx + ty + j) * H_SZ + by + tx] = tile[tx][ty + j];
}

// ---------------------------------------------------------------------------
// Phase 1 (per chunk): cur[m][h] = sum_k X[m][k]*Wi[h][k], fp64 accumulate.
// BM=BN=64, BK=16, 128 threads, per-thread 8x4 fp64 tile (64 acc VGPRs).
// LDS fp32 (exact cvt at use), float4 reads (ds_read_b128).
// k-order sequential -> deterministic, ~fp64-exact (matched ref, absmax 0).
// ---------------------------------------------------------------------------
#define GBM 64
#define GBN 64
#define GBK 16

__global__ __launch_bounds__(128) void gemm_xwi_f64(const float* __restrict__ X,
                                                    const float* __restrict__ Wi,
                                                    double* __restrict__ cur) {
    __shared__ float As[GBK][GBM + 4];   // stride 68 floats = 272 B (16B-aligned)
    __shared__ float Bs[GBK][GBN + 4];

    const int bm = blockIdx.x * GBM;    // 160 m-tiles
    const int bn = blockIdx.y * GBN;    // 4 n-tiles
    const int tid = threadIdx.x;
    const int tx = tid % 16;            // n: 16*4 = 64
    const int ty = tid / 16;            // m: 8*8  = 64

    double acc[8][4] = {};

    const float* Arow = X  + (size_t)bm * N_INP;
    const float* Brow = Wi + (size_t)bn * N_INP;

    for (int k0 = 0; k0 < N_INP; k0 += GBK) {
        // stage A & B tiles: each 64 rows x 16 k = 256 float4; 2/thread each
        #pragma unroll
        for (int i = 0; i < 2; ++i) {
            int s  = tid + i * 128;
            int r  = s >> 2;
            int kc = (s & 3) * 4;
            float4 va = *(const float4*)(Arow + (size_t)r * N_INP + k0 + kc);
            As[kc + 0][r] = va.x; As[kc + 1][r] = va.y;
            As[kc + 2][r] = va.z; As[kc + 3][r] = va.w;
            float4 vb = *(const float4*)(Brow + (size_t)r * N_INP + k0 + kc);
            Bs[kc + 0][r] = vb.x; Bs[kc + 1][r] = vb.y;
            Bs[kc + 2][r] = vb.z; Bs[kc + 3][r] = vb.w;
        }
        __syncthreads();

        #pragma unroll
        for (int kk = 0; kk < GBK; ++kk) {
            float4 af0 = *(const float4*)&As[kk][ty * 8];
            float4 af1 = *(const float4*)&As[kk][ty * 8 + 4];
            float4 bf  = *(const float4*)&Bs[kk][tx * 4];
            double a[8], b[4];
            a[0] = (double)af0.x; a[1] = (double)af0.y;
            a[2] = (double)af0.z; a[3] = (double)af0.w;
            a[4] = (double)af1.x; a[5] = (double)af1.y;
            a[6] = (double)af1.z; a[7] = (double)af1.w;
            b[0] = (double)bf.x;  b[1] = (double)bf.y;
            b[2] = (double)bf.z;  b[3] = (double)bf.w;
            #pragma unroll
            for (int im = 0; im < 8; ++im)
                #pragma unroll
                for (int in = 0; in < 4; ++in)
                    acc[im][in] = fma(a[im], b[in], acc[im][in]);
        }
        __syncthreads();
    }

    #pragma unroll
    for (int im = 0; im < 8; ++im) {
        int m = bm + ty * 8 + im;
        double* dst = cur + (size_t)m * H_SZ + bn + tx * 4;
        ((double2*)dst)[0] = double2{acc[im][0], acc[im][1]};
        ((double2*)dst)[1] = double2{acc[im][2], acc[im][3]};
    }
}

// ---------------------------------------------------------------------------
// Phase 2 (per chunk): 10 LIF steps in fp64, block = batch, thread h = neuron.
// Recurrent gather driven by a dense active-k list built from wave ballots
// (prefix-sum via popcount) -> counted, unrollable, latency-hidden loads.
// ---------------------------------------------------------------------------
__device__ __forceinline__ void build_list(const unsigned long long* zm, int h,
                                           int* listS, int* nactS) {
    unsigned long long w0 = zm[0], w1 = zm[1], w2 = zm[2], w3 = zm[3];
    int wi = h >> 6;
    unsigned long long word = zm[wi];
    int base = 0;
    if (wi > 0) base += __popcll(w0);
    if (wi > 1) base += __popcll(w1);
    if (wi > 2) base += __popcll(w2);
    int bit = h & 63;
    bool act = (word >> bit) & 1ull;
    int pos = __popcll(word & ((1ull << bit) - 1ull));
    if (act) listS[base + pos] = h;
    if (h == 0) *nactS = __popcll(w0) + __popcll(w1) + __popcll(w2) + __popcll(w3);
}

__global__ __launch_bounds__(256) void snn_steps(const double* __restrict__ cur,
                                                 const float* __restrict__ WrT,
                                                 const float* __restrict__ Wout,
                                                 const float* __restrict__ bout,
                                                 float* __restrict__ out,
                                                 double* __restrict__ v_st,
                                                 double* __restrict__ syn_st,
                                                 int* __restrict__ cnt_st,
                                                 unsigned long long* __restrict__ zmask_st,
                                                 int init, int fin) {
    const int b = blockIdx.x;
    const int h = threadIdx.x;

    __shared__ unsigned long long zmaskS[4];
    __shared__ int listS[H_SZ];
    __shared__ int nactS;
    __shared__ float cntS[H_SZ];

    double v, syn;
    int cnt;
    if (init) {
        if (h < 4) zmaskS[h] = 0ull;
        if (h == 0) nactS = 0;
        v = 0.0; syn = 0.0; cnt = 0;
        __syncthreads();
    } else {
        if (h < 4) zmaskS[h] = zmask_st[(size_t)b * 4 + h];
        v   = v_st[(size_t)b * H_SZ + h];
        syn = syn_st[(size_t)b * H_SZ + h];
        cnt = cnt_st[(size_t)b * H_SZ + h];
        __syncthreads();
        build_list(zmaskS, h, listS, &nactS);
        __syncthreads();
    }

    const double* curb = cur + (size_t)b * H_SZ + h;
    const float*  wrh  = WrT + h;

    for (int t = 0; t < T_CHUNK; ++t) {
        // LIF dynamics, reference op order, fp64
        double v_dec = v + 0.05 * ((0.0 - v) + syn);
        double i_dec = 0.9 * syn;
        bool   z_new = v_dec > 0.5;
        v = z_new ? 0.0 : v_dec;
        cnt += z_new ? 1 : 0;

        // recurrent drive from z_prev via dense list (ascending k)
        double rec = 0.0;
        int nact = nactS;
        int j = 0;
        for (; j + 4 <= nact; j += 4) {
            int k0 = listS[j], k1 = listS[j + 1], k2 = listS[j + 2], k3 = listS[j + 3];
            float f0 = wrh[(size_t)k0 * H_SZ];
            float f1 = wrh[(size_t)k1 * H_SZ];
            float f2 = wrh[(size_t)k2 * H_SZ];
            float f3 = wrh[(size_t)k3 * H_SZ];
            rec += (double)f0; rec += (double)f1;
            rec += (double)f2; rec += (double)f3;
        }
        for (; j < nact; ++j)
            rec += (double)wrh[(size_t)listS[j] * H_SZ];

        double inp = curb[(size_t)t * B_SZ * H_SZ];

        __syncthreads();                         // list/mask reads done
        unsigned long long bal = __ballot((int)z_new);
        if ((h & 63) == 0) zmaskS[h >> 6] = bal;
        __syncthreads();                         // new mask visible
        build_list(zmaskS, h, listS, &nactS);
        syn = (i_dec + inp) + rec;
        __syncthreads();                         // new list visible
    }

    v_st[(size_t)b * H_SZ + h]   = v;
    syn_st[(size_t)b * H_SZ + h] = syn;
    cnt_st[(size_t)b * H_SZ + h] = cnt;
    if (h < 4) zmask_st[(size_t)b * 4 + h] = zmaskS[h];

    if (fin) {
        cntS[h] = (float)cnt;
        __syncthreads();
        if (h < L_SZ) {
            double s = 0.0;
            for (int k = 0; k < H_SZ; ++k)
                s += (double)cntS[k] * (double)Wout[(size_t)h * H_SZ + k];
            s += (double)T_STEPS * (double)bout[h];
            out[(size_t)b * L_SZ + h] = (float)(s / (double)T_STEPS);
        }
    }
}

// ---------------------------------------------------------------------------
extern "C" void kernel_launch(void* const* d_in, const int* in_sizes, int n_in,
                              void* d_out, int out_size, void* d_ws, size_t ws_size,
                              hipStream_t stream) {
    const float* x    = (const float*)d_in[0];   // [50,1024,784]
    const float* Wi   = (const float*)d_in[1];   // [256,784]
    const float* Wr   = (const float*)d_in[2];   // [256,256]
    const float* Wout = (const float*)d_in[3];   // [10,256]
    const float* bout = (const float*)d_in[4];   // [10]
    float* out = (float*)d_out;                  // [1024,10]

    // ws layout (~26.5 MB, proven safe)
    char* ws = (char*)d_ws;
    double*             cur_c    = (double*)(ws);                         // 20,971,520 B
    double*             v_st     = (double*)(ws + 20971520);              //  2,097,152 B
    double*             syn_st   = (double*)(ws + 23068672);              //  2,097,152 B
    int*                cnt_st   = (int*)   (ws + 25165824);              //  1,048,576 B
    unsigned long long* zmask_st = (unsigned long long*)(ws + 26214400);  //     32,768 B
    float*              WrT      = (float*) (ws + 26247168);              //    262,144 B

    hipLaunchKernelGGL(transpose_wr, dim3(8, 8), dim3(256), 0, stream, Wr, WrT);

    for (int c = 0; c < 5; ++c) {
        const float* xc = x + (size_t)c * M_CHUNK * N_INP;
        hipLaunchKernelGGL(gemm_xwi_f64, dim3(M_CHUNK / GBM, H_SZ / GBN), dim3(128),
                           0, stream, xc, Wi, cur_c);
        hipLaunchKernelGGL(snn_steps, dim3(B_SZ), dim3(256), 0, stream,
                           cur_c, WrT, Wout, bout, out,
                           v_st, syn_st, cnt_st, zmask_st,
                           (c == 0) ? 1 : 0, (c == 4) ? 1 : 0);
    }
}

// Round 4
// 620.930 us; speedup vs baseline: 1.8369x; 1.7517x over previous
//
#include <hip/hip_runtime.h>
#include <cstdint>
#include <cstddef>

#define T_STEPS 50
#define B_SZ    1024
#define N_INP   784
#define H_SZ    256
#define L_SZ    10
#define T_CHUNK 10                 // 5 chunks of 10 steps
#define M_CHUNK (T_CHUNK * B_SZ)   // 10240 rows per chunk
#define KP      800                // K padded to 25*32
#define XSTRIDE 832                // LDS X row stride (bytes): 16B-aligned, 2-way-bank (free)
#define NSLICE  6

typedef int v4i  __attribute__((ext_vector_type(4)));
typedef int v16i __attribute__((ext_vector_type(16)));

// ---------------------------------------------------------------------------
// Phase 0a: transpose Wr[h][k] (256x256, fp32) -> WrT[k][h] for the scan.
// ---------------------------------------------------------------------------
__global__ __launch_bounds__(256) void transpose_wr(const float* __restrict__ Wr,
                                                    float* __restrict__ WrT) {
    __shared__ float tile[32][33];
    int bx = blockIdx.x * 32, by = blockIdx.y * 32;
    int tx = threadIdx.x % 32, ty = threadIdx.x / 32;   // 32 x 8
    #pragma unroll
    for (int j = 0; j < 32; j += 8)
        tile[ty + j][tx] = Wr[(size_t)(by + ty + j) * H_SZ + bx + tx];
    __syncthreads();
    #pragma unroll
    for (int j = 0; j < 32; j += 8)
        WrT[(size_t)(bx + ty + j) * H_SZ + by + tx] = tile[tx][ty + j];
}

// ---------------------------------------------------------------------------
// Phase 0b: decompose Wi into 6 signed-int8 base-256 digit slices of
// W_fixed = llrint(Wi * 2^40).  Sum_j d_j*2^(8j) == W_fixed exactly.
// SB[j][h][k] with k padded to KP (pad = 0). Residual Wi - W_fixed*2^-40 is
// exactly 0 for |Wi| >= 2^-17 (fp32 ulp >= 2^-40), else < 2^-41: negligible.
// ---------------------------------------------------------------------------
__global__ __launch_bounds__(256) void prep_slices(const float* __restrict__ Wi,
                                                   uint8_t* __restrict__ SB) {
    int h = blockIdx.x;            // 256
    int t = threadIdx.x;           // covers 200 u8x4 groups
    if (t >= KP / 4) return;
    int k = t * 4;
    uint8_t d[NSLICE][4] = {};
    if (k < N_INP) {
        #pragma unroll
        for (int u = 0; u < 4; ++u) {
            double w = (double)Wi[(size_t)h * N_INP + k + u];
            long long wf = llrint(w * 0x1p40);
            #pragma unroll
            for (int j = 0; j < NSLICE; ++j) {
                int8_t dj = (int8_t)(wf & 0xFF);   // balanced low digit
                d[j][u] = (uint8_t)dj;
                wf = (wf - dj) >> 8;
            }
        }
    }
    #pragma unroll
    for (int j = 0; j < NSLICE; ++j)
        *(uchar4*)&SB[(size_t)j * H_SZ * KP + (size_t)h * KP + k] = *(const uchar4*)d[j];
}

// ---------------------------------------------------------------------------
// Phase 1 (per chunk): cur[m][h] = sum_k X[m][k]*Wi[h][k] via 6 exact
// int8-slice MFMAs. Block 256 thr = 4 waves (2m x 2n), tile M=64, H=64.
// X staged fp32->int8 into LDS once per block (full K), B-frags from L2.
// ---------------------------------------------------------------------------
__global__ __launch_bounds__(256) void gemm_i8(const float* __restrict__ X,
                                               const uint8_t* __restrict__ SB,
                                               double* __restrict__ cur) {
    __shared__ uint8_t Xs[64][XSTRIDE];

    const int bm   = blockIdx.x * 64;
    const int bn   = blockIdx.y * 64;
    const int tid  = threadIdx.x;
    const int wave = tid >> 6;
    const int lane = tid & 63;
    const int mw   = (wave & 1) * 32;
    const int nw   = (wave >> 1) * 32;

    // --- stage X tile: 64 rows x 784 fp32 -> int8, zero-pad to 800 ---
    for (int s = tid; s < 64 * (XSTRIDE / 4); s += 256) {
        int r = s / (XSTRIDE / 4);
        int k = (s % (XSTRIDE / 4)) * 4;
        uchar4 b = {0, 0, 0, 0};
        if (k < N_INP) {
            float4 f = *(const float4*)(X + (size_t)(bm + r) * N_INP + k);
            b.x = f.x != 0.f; b.y = f.y != 0.f;
            b.z = f.z != 0.f; b.w = f.w != 0.f;
        }
        *(uchar4*)&Xs[r][k] = b;
    }
    __syncthreads();

    // fragment pointers (verified gfx950 layout: m/n = lane&31, k = (lane>>5)*16 + byte)
    const uint8_t* arow = &Xs[mw + (lane & 31)][(lane >> 5) * 16];
    const int hB = bn + nw + (lane & 31);
    const uint8_t* bp = SB + (size_t)hB * KP + (lane >> 5) * 16;
    const uint8_t* bj[NSLICE];
    #pragma unroll
    for (int j = 0; j < NSLICE; ++j) bj[j] = bp + (size_t)j * H_SZ * KP;

    v16i acc[NSLICE] = {};

    #pragma unroll
    for (int k0 = 0; k0 < KP; k0 += 32) {
        v4i a = *(const v4i*)(arow + k0);
        #pragma unroll
        for (int j = 0; j < NSLICE; ++j) {
            v4i b = *(const v4i*)(bj[j] + k0);
            acc[j] = __builtin_amdgcn_mfma_i32_32x32x32_i8(a, b, acc[j], 0, 0, 0);
        }
    }

    // --- recombine digits in fp64 (each acc exact, |acc| < 2^17) and store ---
    #pragma unroll
    for (int r = 0; r < 16; ++r) {
        int m = bm + mw + (r & 3) + 8 * (r >> 2) + 4 * (lane >> 5);
        int h = bn + nw + (lane & 31);
        double v = (double)acc[0][r] * 0x1p-40
                 + (double)acc[1][r] * 0x1p-32
                 + (double)acc[2][r] * 0x1p-24
                 + (double)acc[3][r] * 0x1p-16
                 + (double)acc[4][r] * 0x1p-8
                 + (double)acc[5][r];
        cur[(size_t)m * H_SZ + h] = v;
    }
}

// ---------------------------------------------------------------------------
// Phase 2 (per chunk): 10 LIF steps in fp64, block = batch, thread h = neuron.
// Dense active-k list from wave ballots; fp64 dynamics (proven absmax 0).
// ---------------------------------------------------------------------------
__device__ __forceinline__ void build_list(const unsigned long long* zm, int h,
                                           int* listS, int* nactS) {
    unsigned long long w0 = zm[0], w1 = zm[1], w2 = zm[2], w3 = zm[3];
    int wi = h >> 6;
    unsigned long long word = zm[wi];
    int base = 0;
    if (wi > 0) base += __popcll(w0);
    if (wi > 1) base += __popcll(w1);
    if (wi > 2) base += __popcll(w2);
    int bit = h & 63;
    bool act = (word >> bit) & 1ull;
    int pos = __popcll(word & ((1ull << bit) - 1ull));
    if (act) listS[base + pos] = h;
    if (h == 0) *nactS = __popcll(w0) + __popcll(w1) + __popcll(w2) + __popcll(w3);
}

__global__ __launch_bounds__(256) void snn_steps(const double* __restrict__ cur,
                                                 const float* __restrict__ WrT,
                                                 const float* __restrict__ Wout,
                                                 const float* __restrict__ bout,
                                                 float* __restrict__ out,
                                                 double* __restrict__ v_st,
                                                 double* __restrict__ syn_st,
                                                 int* __restrict__ cnt_st,
                                                 unsigned long long* __restrict__ zmask_st,
                                                 int init, int fin) {
    const int b = blockIdx.x;
    const int h = threadIdx.x;

    __shared__ unsigned long long zmaskS[4];
    __shared__ int listS[H_SZ];
    __shared__ int nactS;
    __shared__ float cntS[H_SZ];

    double v, syn;
    int cnt;
    if (init) {
        if (h < 4) zmaskS[h] = 0ull;
        if (h == 0) nactS = 0;
        v = 0.0; syn = 0.0; cnt = 0;
        __syncthreads();
    } else {
        if (h < 4) zmaskS[h] = zmask_st[(size_t)b * 4 + h];
        v   = v_st[(size_t)b * H_SZ + h];
        syn = syn_st[(size_t)b * H_SZ + h];
        cnt = cnt_st[(size_t)b * H_SZ + h];
        __syncthreads();
        build_list(zmaskS, h, listS, &nactS);
        __syncthreads();
    }

    const double* curb = cur + (size_t)b * H_SZ + h;
    const float*  wrh  = WrT + h;

    for (int t = 0; t < T_CHUNK; ++t) {
        double v_dec = v + 0.05 * ((0.0 - v) + syn);
        double i_dec = 0.9 * syn;
        bool   z_new = v_dec > 0.5;
        v = z_new ? 0.0 : v_dec;
        cnt += z_new ? 1 : 0;

        double rec = 0.0;
        int nact = nactS;
        int j = 0;
        for (; j + 4 <= nact; j += 4) {
            int k0 = listS[j], k1 = listS[j + 1], k2 = listS[j + 2], k3 = listS[j + 3];
            float f0 = wrh[(size_t)k0 * H_SZ];
            float f1 = wrh[(size_t)k1 * H_SZ];
            float f2 = wrh[(size_t)k2 * H_SZ];
            float f3 = wrh[(size_t)k3 * H_SZ];
            rec += (double)f0; rec += (double)f1;
            rec += (double)f2; rec += (double)f3;
        }
        for (; j < nact; ++j)
            rec += (double)wrh[(size_t)listS[j] * H_SZ];

        double inp = curb[(size_t)t * B_SZ * H_SZ];

        __syncthreads();
        unsigned long long bal = __ballot((int)z_new);
        if ((h & 63) == 0) zmaskS[h >> 6] = bal;
        __syncthreads();
        build_list(zmaskS, h, listS, &nactS);
        syn = (i_dec + inp) + rec;
        __syncthreads();
    }

    v_st[(size_t)b * H_SZ + h]   = v;
    syn_st[(size_t)b * H_SZ + h] = syn;
    cnt_st[(size_t)b * H_SZ + h] = cnt;
    if (h < 4) zmask_st[(size_t)b * 4 + h] = zmaskS[h];

    if (fin) {
        cntS[h] = (float)cnt;
        __syncthreads();
        if (h < L_SZ) {
            double s = 0.0;
            for (int k = 0; k < H_SZ; ++k)
                s += (double)cntS[k] * (double)Wout[(size_t)h * H_SZ + k];
            s += (double)T_STEPS * (double)bout[h];
            out[(size_t)b * L_SZ + h] = (float)(s / (double)T_STEPS);
        }
    }
}

// ---------------------------------------------------------------------------
extern "C" void kernel_launch(void* const* d_in, const int* in_sizes, int n_in,
                              void* d_out, int out_size, void* d_ws, size_t ws_size,
                              hipStream_t stream) {
    const float* x    = (const float*)d_in[0];   // [50,1024,784]
    const float* Wi   = (const float*)d_in[1];   // [256,784]
    const float* Wr   = (const float*)d_in[2];   // [256,256]
    const float* Wout = (const float*)d_in[3];   // [10,256]
    const float* bout = (const float*)d_in[4];   // [10]
    float* out = (float*)d_out;                  // [1024,10]

    // ws layout (~27.7 MB, proven safe)
    char* ws = (char*)d_ws;
    double*             cur_c    = (double*)(ws);                         // 20,971,520 B
    double*             v_st     = (double*)(ws + 20971520);              //  2,097,152 B
    double*             syn_st   = (double*)(ws + 23068672);              //  2,097,152 B
    int*                cnt_st   = (int*)   (ws + 25165824);              //  1,048,576 B
    unsigned long long* zmask_st = (unsigned long long*)(ws + 26214400);  //     32,768 B
    float*              WrT      = (float*) (ws + 26247168);              //    262,144 B
    uint8_t*            SB       = (uint8_t*)(ws + 26509312);             //  1,228,800 B

    hipLaunchKernelGGL(transpose_wr, dim3(8, 8), dim3(256), 0, stream, Wr, WrT);
    hipLaunchKernelGGL(prep_slices, dim3(H_SZ), dim3(256), 0, stream, Wi, SB);

    for (int c = 0; c < 5; ++c) {
        const float* xc = x + (size_t)c * M_CHUNK * N_INP;
        hipLaunchKernelGGL(gemm_i8, dim3(M_CHUNK / 64, H_SZ / 64), dim3(256),
                           0, stream, xc, SB, cur_c);
        hipLaunchKernelGGL(snn_steps, dim3(B_SZ), dim3(256), 0, stream,
                           cur_c, WrT, Wout, bout, out,
                           v_st, syn_st, cnt_st, zmask_st,
                           (c == 0) ? 1 : 0, (c == 4) ? 1 : 0);
    }
}

// Round 5
// 482.130 us; speedup vs baseline: 2.3657x; 1.2879x over previous
//
#include <hip/hip_runtime.h>
#include <cstdint>
#include <cstddef>

#define T_STEPS 50
#define B_SZ    1024
#define N_INP   784
#define H_SZ    256
#define L_SZ    10
#define M_TOT   (T_STEPS * B_SZ)   // 51200
#define NK0     26                 // K padded to 26*32 = 832 (784 = 49*16, group-aligned)
#define NSLICE  5                  // 5 balanced base-256 digits of rint(Wi*2^40): exact for |Wi|<0.5

typedef int v4i  __attribute__((ext_vector_type(4)));
typedef int v16i __attribute__((ext_vector_type(16)));

// ---------------------------------------------------------------------------
// Phase 0a: transpose Wr[h][k] (256x256, fp32) -> WrT[k][h] for the scan.
// ---------------------------------------------------------------------------
__global__ __launch_bounds__(256) void transpose_wr(const float* __restrict__ Wr,
                                                    float* __restrict__ WrT) {
    __shared__ float tile[32][33];
    int bx = blockIdx.x * 32, by = blockIdx.y * 32;
    int tx = threadIdx.x % 32, ty = threadIdx.x / 32;   // 32 x 8
    #pragma unroll
    for (int j = 0; j < 32; j += 8)
        tile[ty + j][tx] = Wr[(size_t)(by + ty + j) * H_SZ + bx + tx];
    __syncthreads();
    #pragma unroll
    for (int j = 0; j < 32; j += 8)
        WrT[(size_t)(bx + ty + j) * H_SZ + by + tx] = tile[tx][ty + j];
}

// ---------------------------------------------------------------------------
// Phase 0b: decompose Wi into 5 balanced int8 digits of rint(Wi*2^40), written
// FRAGMENT-LINEAR: SBp[((nt*26+k0)*5+j)*1024 + lane*16 + byte], where
//   h = nt*32 + (lane&31),  k = k0*32 + (lane>>5)*16 + byte.
// So the gemm's B loads are fully coalesced 1KB reads. Exact: |Wi|<0.5 means
// digit 5 of the balanced expansion is always 0 (proven bound), and fixed
// point 2^-40 represents fp32 exactly for |w|>=2^-17 (residual < 2^-41,
// negligible — same analysis as R4 which hit absmax 0).
// Grid (8 nt, 13 k0-pairs), 128 threads: t>>6 picks k0 within pair.
// ---------------------------------------------------------------------------
__global__ __launch_bounds__(128) void prep_packed(const float* __restrict__ Wi,
                                                   uint8_t* __restrict__ SBp) {
    const int nt   = blockIdx.x;
    const int k0   = blockIdx.y * 2 + (threadIdx.x >> 6);
    const int lane = threadIdx.x & 63;
    const int h    = nt * 32 + (lane & 31);
    const int g    = k0 * 2 + (lane >> 5);     // 16-float group index

    int wd[NSLICE][4] = {};
    #pragma unroll
    for (int u = 0; u < 16; ++u) {
        double wv = 0.0;
        if (g < 49) wv = (double)Wi[(size_t)h * N_INP + g * 16 + u];
        double r = rint(wv * 0x1p40);          // exact scaling, ties-to-even
        #pragma unroll
        for (int j = 0; j < NSLICE - 1; ++j) {
            double q  = floor((r + 128.0) * 0.00390625);   // /256, exact steps
            double dj = r - 256.0 * q;                     // in [-128,127]
            wd[j][u >> 2] |= ((int)dj & 0xFF) << ((u & 3) * 8);
            r = q;
        }
        wd[NSLICE - 1][u >> 2] |= ((int)r & 0xFF) << ((u & 3) * 8);
    }
    uint8_t* base = SBp + ((size_t)(nt * NK0 + k0) * NSLICE) * 1024 + lane * 16;
    #pragma unroll
    for (int j = 0; j < NSLICE; ++j)
        *(v4i*)(base + (size_t)j * 1024) = (v4i){wd[j][0], wd[j][1], wd[j][2], wd[j][3]};
}

// ---------------------------------------------------------------------------
// Phase 1: cur[m][h] = sum_k X[m][k]*Wi[h][k] exactly, via 5 int8-digit MFMAs.
// Block = 256 thr = 4 waves = 4 m-tiles (M=128). Each wave holds its FULL
// A-strip in registers (26 x v4i = 104 VGPR), X read once. Loop nt=0..7:
// B staged per k0-pair (10KB) into LDS, shared by all 4 waves (coalesced
// 16B/lane loads — kills R4's 32x L2 transaction shatter). acc recombined in
// fp64 (all intermediates integers < 2^48: exact) and stored.
// ---------------------------------------------------------------------------
__global__ __launch_bounds__(256, 2) void gemm_i8p(const float* __restrict__ X,
                                                   const uint8_t* __restrict__ SBp,
                                                   double* __restrict__ cur) {
    __shared__ __align__(16) uint8_t Bs[2 * NSLICE * 1024];   // 10 KB (one k0-pair)

    const int tid   = threadIdx.x;
    const int wave  = tid >> 6;
    const int lane  = tid & 63;
    const int ghalf = lane >> 5;
    const int bm    = blockIdx.x * 128;
    const int m     = bm + wave * 32 + (lane & 31);

    // --- load + convert A-strip: 26 x 16 bytes (binary fp32 -> i8) ---
    v4i a[NK0];
    #pragma unroll
    for (int k0 = 0; k0 < NK0; ++k0) {
        int g = k0 * 2 + ghalf;
        unsigned int bw[4] = {0u, 0u, 0u, 0u};
        if (g < 49) {
            const float* src = X + (size_t)m * N_INP + g * 16;
            #pragma unroll
            for (int q = 0; q < 4; ++q) {
                float4 f = *(const float4*)(src + q * 4);
                bw[q] = (f.x != 0.f ? 1u : 0u) | (f.y != 0.f ? 0x100u : 0u)
                      | (f.z != 0.f ? 0x10000u : 0u) | (f.w != 0.f ? 0x1000000u : 0u);
            }
        }
        a[k0] = (v4i){(int)bw[0], (int)bw[1], (int)bw[2], (int)bw[3]};
    }

    for (int nt = 0; nt < 8; ++nt) {
        v16i acc[NSLICE] = {};
        const uint8_t* bsrc = SBp + ((size_t)nt * NK0 * NSLICE) * 1024;

        #pragma unroll
        for (int k0p = 0; k0p < 13; ++k0p) {
            __syncthreads();   // previous pair's reads done
            // stage 10,240 B = 640 x 16B slots
            const uint8_t* src = bsrc + (size_t)(k0p * 2) * NSLICE * 1024;
            #pragma unroll
            for (int i = 0; i < 3; ++i) {
                int s = tid + i * 256;
                if (s < 2 * NSLICE * 64)
                    *(v4i*)(Bs + s * 16) = *(const v4i*)(src + s * 16);
            }
            __syncthreads();   // pair staged
            #pragma unroll
            for (int dk = 0; dk < 2; ++dk) {
                v4i aa = a[k0p * 2 + dk];
                #pragma unroll
                for (int j = 0; j < NSLICE; ++j) {
                    v4i bb = *(const v4i*)(Bs + (dk * NSLICE + j) * 1024 + lane * 16);
                    acc[j] = __builtin_amdgcn_mfma_i32_32x32x32_i8(aa, bb, acc[j], 0, 0, 0);
                }
            }
        }

        // recombine digits (exact integer Horner in fp64) and store
        const int h = nt * 32 + (lane & 31);
        #pragma unroll
        for (int r = 0; r < 16; ++r) {
            double s = (double)acc[4][r];
            s = s * 256.0 + (double)acc[3][r];
            s = s * 256.0 + (double)acc[2][r];
            s = s * 256.0 + (double)acc[1][r];
            s = s * 256.0 + (double)acc[0][r];
            int mr = bm + wave * 32 + (r & 3) + 8 * (r >> 2) + 4 * ghalf;
            cur[(size_t)mr * H_SZ + h] = s * 0x1p-40;
        }
    }
}

// ---------------------------------------------------------------------------
// Phase 2: 50 LIF steps in fp64, one dispatch. Block = batch, thread h =
// neuron. Ping-pong mask/list -> 2 barriers/step. Gather via dense active-k
// list (prefix-sum from wave ballots), unrolled, 2 fp64 accumulators.
// ---------------------------------------------------------------------------
__device__ __forceinline__ void build_list(const unsigned long long* zm, int h,
                                           int* listS, int* nactS) {
    unsigned long long w0 = zm[0], w1 = zm[1], w2 = zm[2], w3 = zm[3];
    int wi = h >> 6;
    unsigned long long word = zm[wi];
    int base = 0;
    if (wi > 0) base += __popcll(w0);
    if (wi > 1) base += __popcll(w1);
    if (wi > 2) base += __popcll(w2);
    int bit = h & 63;
    bool act = (word >> bit) & 1ull;
    int pos = __popcll(word & ((1ull << bit) - 1ull));
    if (act) listS[base + pos] = h;
    if (h == 0) *nactS = __popcll(w0) + __popcll(w1) + __popcll(w2) + __popcll(w3);
}

__global__ __launch_bounds__(256) void snn_scan(const double* __restrict__ cur,
                                                const float* __restrict__ WrT,
                                                const float* __restrict__ Wout,
                                                const float* __restrict__ bout,
                                                float* __restrict__ out) {
    const int b = blockIdx.x;
    const int h = threadIdx.x;

    __shared__ unsigned long long zm[2][4];
    __shared__ int listS[2][H_SZ];
    __shared__ int nactS[2];
    __shared__ float cntS[H_SZ];

    if (h == 0) { nactS[0] = 0; nactS[1] = 0; }
    __syncthreads();

    double v = 0.0, syn = 0.0;
    int cnt = 0;
    const double* curb = cur + (size_t)b * H_SZ + h;
    const float*  wrh  = WrT + h;

    for (int t = 0; t < T_STEPS; ++t) {
        const int p = t & 1;
        // LIF dynamics, reference op order, fp64
        double v_dec = v + 0.05 * ((0.0 - v) + syn);
        double i_dec = 0.9 * syn;
        bool   z_new = v_dec > 0.5;
        v = z_new ? 0.0 : v_dec;
        cnt += z_new ? 1 : 0;

        // recurrent drive from z_prev via dense list
        double rec0 = 0.0, rec1 = 0.0;
        const int  n  = nactS[p];
        const int* lp = listS[p];
        int j = 0;
        for (; j + 4 <= n; j += 4) {
            int k0 = lp[j], k1 = lp[j + 1], k2 = lp[j + 2], k3 = lp[j + 3];
            float f0 = wrh[(size_t)k0 * H_SZ];
            float f1 = wrh[(size_t)k1 * H_SZ];
            float f2 = wrh[(size_t)k2 * H_SZ];
            float f3 = wrh[(size_t)k3 * H_SZ];
            rec0 += (double)f0 + (double)f1;
            rec1 += (double)f2 + (double)f3;
        }
        for (; j < n; ++j)
            rec0 += (double)wrh[(size_t)lp[j] * H_SZ];

        double inp = curb[(size_t)t * B_SZ * H_SZ];

        unsigned long long bal = __ballot((int)z_new);
        if ((h & 63) == 0) zm[p ^ 1][h >> 6] = bal;
        __syncthreads();                     // new mask published
        build_list(zm[p ^ 1], h, listS[p ^ 1], &nactS[p ^ 1]);
        syn = (i_dec + inp) + (rec0 + rec1);
        __syncthreads();                     // new list complete
    }

    cntS[h] = (float)cnt;
    __syncthreads();
    if (h < L_SZ) {
        double s = 0.0;
        for (int k = 0; k < H_SZ; ++k)
            s += (double)cntS[k] * (double)Wout[(size_t)h * H_SZ + k];
        s += (double)T_STEPS * (double)bout[h];
        out[(size_t)b * L_SZ + h] = (float)(s / (double)T_STEPS);
    }
}

// ---------------------------------------------------------------------------
extern "C" void kernel_launch(void* const* d_in, const int* in_sizes, int n_in,
                              void* d_out, int out_size, void* d_ws, size_t ws_size,
                              hipStream_t stream) {
    const float* x    = (const float*)d_in[0];   // [50,1024,784]
    const float* Wi   = (const float*)d_in[1];   // [256,784]
    const float* Wr   = (const float*)d_in[2];   // [256,256]
    const float* Wout = (const float*)d_in[3];   // [10,256]
    const float* bout = (const float*)d_in[4];   // [10]
    float* out = (float*)d_out;                  // [1024,10]

    // ws layout (~106.2 MB; ws is ~642 MB per the poison-fill WRITE_SIZE)
    char* ws = (char*)d_ws;
    double*  cur = (double*)(ws);                        // 51200*256*8 = 104,857,600 B
    float*   WrT = (float*)(ws + 104857600);             //      262,144 B
    uint8_t* SBp = (uint8_t*)(ws + 105119744);           // 8*26*5*1024 = 1,064,960 B

    hipLaunchKernelGGL(transpose_wr, dim3(8, 8), dim3(256), 0, stream, Wr, WrT);
    hipLaunchKernelGGL(prep_packed, dim3(8, 13), dim3(128), 0, stream, Wi, SBp);
    hipLaunchKernelGGL(gemm_i8p, dim3(M_TOT / 128), dim3(256), 0, stream, x, SBp, cur);
    hipLaunchKernelGGL(snn_scan, dim3(B_SZ), dim3(256), 0, stream,
                       cur, WrT, Wout, bout, out);
}